// Round 13
// baseline (125.545 us; speedup 1.0000x reference)
//
#include <hip/hip_runtime.h>
#include <math.h>

#define B_DIM 8
#define S_DIM 4096
#define D_DIM 1024
#define N_DIM 16
#define ROWS (B_DIM * S_DIM)          // 32768

#define CHUNK_L 32
#define WARM 64
#define STEPS (CHUNK_L + WARM)        // 96
#define NCHAIN (B_DIM * (S_DIM / CHUNK_L))   // 1024 chains

#define XB_BLOCKS (ROWS / 64)          // 512 (64 rows per block, 16/wave)
#define CW_BLOCKS ((N_DIM * D_DIM) / 256)   // 64

typedef float f32x4 __attribute__((ext_vector_type(4)));
typedef int i32x4 __attribute__((ext_vector_type(4)));

__device__ __forceinline__ void gl_lds16(const float* g, float* l) {
    __builtin_amdgcn_global_load_lds(
        (const __attribute__((address_space(1))) void*)g,
        (__attribute__((address_space(3))) void*)l, 16, 0, 0);
}

// D = A*B + D via 3 bf16 MFMAs: Ah*Bh + Al*Bh + Ah*Bl (lo*lo dropped, ~2^-16).
// Inline asm (not builtin): immune to builtin operand-type mismatch (suspected
// R2/R3 crash cause). s_nop 1 covers VALU-write -> MFMA-read; same-acc MFMA
// chaining needs no waits.
__device__ __forceinline__ void mfma3(f32x4& acc, i32x4 ah, i32x4 al,
                                      i32x4 bh, i32x4 bl) {
    asm volatile(
        "s_nop 1\n\t"
        "v_mfma_f32_16x16x32_bf16 %0, %1, %3, %0\n\t"
        "v_mfma_f32_16x16x32_bf16 %0, %2, %3, %0\n\t"
        "v_mfma_f32_16x16x32_bf16 %0, %1, %4, %0"
        : "+v"(acc)
        : "v"(ah), "v"(al), "v"(bh), "v"(bl));
}

// split fp32 -> (hi, lo) bf16 top-16-bit truncations; residual < 2^-16 rel.
__device__ __forceinline__ void split1(float v, unsigned& h, unsigned& lo) {
    unsigned u = __float_as_uint(v);
    h = u >> 16;
    float fh = __uint_as_float(u & 0xFFFF0000u);
    lo = __float_as_uint(v - fh) >> 16;
}

__device__ __forceinline__ void pack8(const float e[8], i32x4& hi, i32x4& lo) {
#pragma unroll
    for (int p = 0; p < 4; ++p) {
        unsigned h0, l0, h1, l1;
        split1(e[2 * p], h0, l0);
        split1(e[2 * p + 1], h1, l1);
        hi[p] = (int)(h0 | (h1 << 16));
        lo[p] = (int)(l0 | (l1 << 16));
    }
}

// B fragment for one K=32 step: lane l holds B[k][n=l&15],
// k = kq*32 + 4*(l>>4)+j (j<4) and +16 (j>=4)  [m156/m162 layout].
__device__ __forceinline__ void loadB(const float* __restrict__ Bm, int kt,
                                      int kq, int l, float be[8]) {
    const float* bp = Bm + (size_t)(kt * 64 + kq * 32 + 4 * (l >> 4)) * N_DIM +
                      (l & 15);
#pragma unroll
    for (int j = 0; j < 4; ++j) {
        be[j] = bp[j * N_DIM];
        be[4 + j] = bp[(16 + j) * N_DIM];
    }
}

// stage 16 rows x 64 k of x into this wave's private LDS region (linear dest,
// pre-swizzled source col-block kb ^ row  -> rule #21 both-sides swizzle).
__device__ __forceinline__ void xb_stage(const float* __restrict__ x,
                                         float* dst, int row0w, int kt, int l) {
    const int lr = l >> 4, kb = l & 15;
#pragma unroll
    for (int i = 0; i < 4; ++i) {
        int rr = i * 4 + lr;
        const float* src = x + (size_t)(row0w + rr) * D_DIM + kt * 64 +
                           ((kb ^ rr) * 4);
        gl_lds16(src, dst + i * 256);
    }
}

// compute one kt (64 k) for this wave's 16x16 tile from LDS buffer xsw.
__device__ __forceinline__ void xb_compute(const float* xsw, int l,
                                           const float be0[8],
                                           const float be1[8], f32x4& acc) {
    const int g = l >> 4, col = l & 15;
#pragma unroll
    for (int kq = 0; kq < 2; ++kq) {
        const int blk0 = (kq * 8 + g) ^ col;
        const int blk1 = (kq * 8 + 4 + g) ^ col;
        f32x4 xa = *(const f32x4*)(xsw + col * 64 + blk0 * 4);
        f32x4 xv = *(const f32x4*)(xsw + col * 64 + blk1 * 4);
        float ae[8] = {xa[0], xa[1], xa[2], xa[3], xv[0], xv[1], xv[2], xv[3]};
        i32x4 ah, al, bh, bl;
        pack8(ae, ah, al);
        pack8(kq ? be1 : be0, bh, bl);
        mfma3(acc, ah, al, bh, bl);
    }
}

// ---------------------------------------------------------------------------
// Kernel 1 (fused): blocks [0,512): xb = x@B via MFMA, 64 rows/block,
// one 16-row M-tile per wave (fully wave-private: no barriers). x staged
// fp32 via gl_lds double-buffer; per K=32: 2 swizzled ds_read_b128 (A),
// 8 L2 dwords (B), hi/lo split, 3 MFMA. Counted vmcnt(4) keeps next tile's
// stage in flight (T4). blocks [512, 576): CW = C @ W^T (round-1 proven).
// ---------------------------------------------------------------------------
__global__ __launch_bounds__(256) void k_xbcw(const float* __restrict__ x,
                                              const float* __restrict__ Bm,
                                              float* __restrict__ xb,
                                              const float* __restrict__ C,
                                              const float* __restrict__ W,
                                              float* __restrict__ CW) {
    const int t = threadIdx.x;
    if (blockIdx.x >= XB_BLOCKS) {
        int u = (blockIdx.x - XB_BLOCKS) * 256 + t;
        int d = u >> 4;
        int n = u & 15;
        const float* crow = C + n * D_DIM;
        const float* wrow = W + (size_t)d * D_DIM;
        float acc = 0.f;
#pragma unroll 4
        for (int k = 0; k < D_DIM; k += 4) {
            float4 c4 = *(const float4*)(crow + k);
            float4 w4 = *(const float4*)(wrow + k);
            acc = fmaf(c4.x, w4.x, acc);
            acc = fmaf(c4.y, w4.y, acc);
            acc = fmaf(c4.z, w4.z, acc);
            acc = fmaf(c4.w, w4.w, acc);
        }
        CW[n * D_DIM + d] = acc;
        return;
    }
    __shared__ float xs[2][4096];          // 2 x 16 KB, [64 rows][64 k]
    const int l = t & 63;
    const int w = t >> 6;
    const int row0w = blockIdx.x * 64 + w * 16;
    float* wbase0 = &xs[0][w * 1024];
    float* wbase1 = &xs[1][w * 1024];

    f32x4 acc = {0.f, 0.f, 0.f, 0.f};
    xb_stage(x, wbase0, row0w, 0, l);

    int cur = 0;
#pragma unroll 1
    for (int kt = 0; kt < 15; ++kt) {
        float be0[8], be1[8];
        loadB(Bm, kt, 0, l, be0);          // B loads issued BEFORE next stage
        loadB(Bm, kt, 1, l, be1);          //   -> vmcnt(4) forces them done
        xb_stage(x, cur ? wbase0 : wbase1, row0w, kt + 1, l);
        __builtin_amdgcn_sched_barrier(0);
        asm volatile("s_waitcnt vmcnt(4)" ::: "memory");
        __builtin_amdgcn_sched_barrier(0);
        xb_compute(cur ? wbase1 : wbase0, l, be0, be1, acc);
        cur ^= 1;
    }
    {   // epilogue kt = 15
        float be0[8], be1[8];
        loadB(Bm, 15, 0, l, be0);
        loadB(Bm, 15, 1, l, be1);
        __builtin_amdgcn_sched_barrier(0);
        asm volatile("s_waitcnt vmcnt(0)" ::: "memory");
        __builtin_amdgcn_sched_barrier(0);
        xb_compute(cur ? wbase1 : wbase0, l, be0, be1, acc);
    }
    asm volatile("s_nop 7\n\ts_nop 7");    // MFMA write -> VALU read gap

    // D layout (m89): col = l&15, row = 4*(l>>4)+reg
    const int g = l >> 4, col = l & 15;
#pragma unroll
    for (int reg = 0; reg < 4; ++reg)
        xb[(size_t)(row0w + g * 4 + reg) * N_DIM + col] = acc[reg];
}

// ---------------------------------------------------------------------------
// Kernel 2: chunked scan (round-6 proven, UNCHANGED)
// ---------------------------------------------------------------------------
__global__ __launch_bounds__(64) void k_scan(const float* __restrict__ xb,
                                             const float* __restrict__ A,
                                             float* __restrict__ hs) {
    const int tid = threadIdx.x;
    const int n = tid & 15;
    const int base4 = (tid & 48) * 4;

    const int chain = blockIdx.x * 4 + (tid >> 4);
    const int b = chain >> 7;
    const int chunk = chain & 127;
    const int t0 = chunk * CHUNK_L - WARM;

    float Ar[16];
#pragma unroll
    for (int m4 = 0; m4 < 16; m4 += 4) {
        float4 v = *(const float4*)(A + n * 16 + m4);
        Ar[m4 + 0] = v.x; Ar[m4 + 1] = v.y; Ar[m4 + 2] = v.z; Ar[m4 + 3] = v.w;
    }

    const float* xp = xb + (size_t)b * S_DIM * N_DIM + n;
    float* hp = hs + (size_t)b * S_DIM * N_DIM + n;

    float ring[8];
#pragma unroll
    for (int i = 0; i < 8; ++i) {
        int tt = t0 + i;
        ring[i] = (tt >= 0) ? xp[(size_t)tt * N_DIM] : 0.f;
    }

    float h = 0.f;
    for (int tr0 = 0; tr0 < STEPS; tr0 += 8) {
#pragma unroll
        for (int j = 0; j < 8; ++j) {
            const int tr = tr0 + j;
            const float xv = ring[j];
            const int hbits = __float_as_int(h);
            int hm[16];
#pragma unroll
            for (int m = 0; m < 16; ++m)
                hm[m] = __builtin_amdgcn_ds_bpermute(base4 + m * 4, hbits);
            float acc0 = xv, acc1 = 0.f;
#pragma unroll
            for (int m = 0; m < 8; ++m) {
                acc0 = fmaf(Ar[m], __int_as_float(hm[m]), acc0);
                acc1 = fmaf(Ar[m + 8], __int_as_float(hm[m + 8]), acc1);
            }
            float g = acc0 + acc1;
            float ax = fabsf(g);
            float e = __expf(2.f * ax);
            float tv = 1.f - 2.f / (e + 1.f);
            h = (g < 0.f) ? -tv : tv;
            if (tr >= WARM)
                hp[(size_t)(t0 + tr) * N_DIM] = h;
            int tt = t0 + tr + 8;
            if (tr + 8 < STEPS)
                ring[j] = (tt >= 0) ? xp[(size_t)tt * N_DIM] : 0.f;
        }
    }
}

// ---------------------------------------------------------------------------
// Kernel 3: out[r][d] = sum_n hs[r][n] * CW[n][d] + bias[d]  (round-1 proven)
// ---------------------------------------------------------------------------
__global__ __launch_bounds__(256) void k_out(const float* __restrict__ hs,
                                             const float* __restrict__ CW,
                                             const float* __restrict__ bias,
                                             float* __restrict__ out) {
    const int t = threadIdx.x;
    const int d0 = t * 4;
    const int row0 = blockIdx.x * 32;
    float4 cw[16];
#pragma unroll
    for (int nn = 0; nn < 16; ++nn)
        cw[nn] = *(const float4*)(CW + nn * D_DIM + d0);
    float4 b4 = *(const float4*)(bias + d0);

    for (int r = row0; r < row0 + 32; ++r) {
        const float4* hp = (const float4*)(hs + (size_t)r * N_DIM);
        float4 h0 = hp[0], h1 = hp[1], h2 = hp[2], h3 = hp[3];
        float hv[16] = {h0.x, h0.y, h0.z, h0.w, h1.x, h1.y, h1.z, h1.w,
                        h2.x, h2.y, h2.z, h2.w, h3.x, h3.y, h3.z, h3.w};
        float4 acc = b4;
#pragma unroll
        for (int nn = 0; nn < 16; ++nn) {
            acc.x = fmaf(hv[nn], cw[nn].x, acc.x);
            acc.y = fmaf(hv[nn], cw[nn].y, acc.y);
            acc.z = fmaf(hv[nn], cw[nn].z, acc.z);
            acc.w = fmaf(hv[nn], cw[nn].w, acc.w);
        }
        *(float4*)(out + (size_t)r * D_DIM + d0) = acc;
    }
}

// ---------------------------------------------------------------------------
extern "C" void kernel_launch(void* const* d_in, const int* in_sizes, int n_in,
                              void* d_out, int out_size, void* d_ws,
                              size_t ws_size, hipStream_t stream) {
    const float* x    = (const float*)d_in[0];   // [8,4096,1024]
    const float* A    = (const float*)d_in[1];   // [16,16]
    const float* Bm   = (const float*)d_in[2];   // [1024,16]
    const float* C    = (const float*)d_in[3];   // [16,1024]
    const float* W    = (const float*)d_in[4];   // [1024,1024]
    const float* bias = (const float*)d_in[5];   // [1024]
    float* out = (float*)d_out;

    float* ws = (float*)d_ws;
    float* xb = ws;                            // 524288 floats
    float* hs = ws + 524288;                   // 524288
    float* CW = ws + 1048576;                  // 16384

    k_xbcw<<<dim3(XB_BLOCKS + CW_BLOCKS), dim3(256), 0, stream>>>(
        x, Bm, xb, C, W, CW);
    k_scan<<<dim3(NCHAIN / 4), dim3(64), 0, stream>>>(xb, A, hs);
    k_out<<<dim3(ROWS / 32), dim3(256), 0, stream>>>(hs, CW, bias, out);
}